// Round 6
// baseline (49.008 us; speedup 1.0000x reference)
//
#include <hip/hip_runtime.h>

#define NUM_IDS   16384
#define EMBED_DIM 128
#define INV_KPROB 1.25f

typedef float  fvec4 __attribute__((ext_vector_type(4)));
typedef unsigned int uvec4 __attribute__((ext_vector_type(4)));

// ---------------- helpers ----------------
static __device__ __forceinline__ unsigned short f2bf(float x) {
    unsigned u = __float_as_uint(x);
    unsigned r = (u + 0x7fffu + ((u >> 16) & 1u)) >> 16;   // RNE
    return (unsigned short)r;
}

// ============ Kernel 1: fused prep ============
// blocks [0, nb_meta)           : row_ptr + packed {col, val}
// blocks [nb_meta, nb_meta+...) : f32 table -> bf16 table (RNE)
// The meta half is latency-bound, the convert half is BW-bound; fusing them
// into one dispatch overlaps the two instead of serializing two launches.
__global__ __launch_bounds__(256) void prep_fused(
    const int*   __restrict__ row_idx,
    const int*   __restrict__ col_idx,
    const float* __restrict__ data,
    const int*   __restrict__ keep,
    int nnz,
    int*  __restrict__ ptr,
    int2* __restrict__ pack,
    const float* __restrict__ emb,
    unsigned short* __restrict__ tab,
    int n8, int nb_meta)
{
    if ((int)blockIdx.x < nb_meta) {
        const int i = blockIdx.x * 256 + threadIdx.x;
        if (i >= nnz) return;

        const int k = keep[i];
        int2 p;
        p.x = k ? col_idx[i] : 0;               // dropped -> cache-hot row 0
        p.y = __float_as_int(k ? data[i] * INV_KPROB : 0.0f);
        pack[i] = p;

        const int b = row_idx[i];
        if (i == 0) {
            for (int r = 0; r <= b; ++r) ptr[r] = 0;
        } else {
            const int a = row_idx[i - 1];
            for (int r = a + 1; r <= b; ++r) ptr[r] = i;
        }
        if (i == nnz - 1) {
            for (int r = b + 1; r <= NUM_IDS; ++r) ptr[r] = nnz;
        }
    } else {
        const int i = (blockIdx.x - nb_meta) * 256 + threadIdx.x;
        if (i >= n8) return;
        // Nontemporal reads: the f32 table is dead after this — don't let it
        // evict the bf16 table we're writing.
        const fvec4* src = reinterpret_cast<const fvec4*>(emb) + 2 * (size_t)i;
        fvec4 a = __builtin_nontemporal_load(src);
        fvec4 b = __builtin_nontemporal_load(src + 1);
        union { unsigned short u[8]; uvec4 v; } r;
        r.u[0] = f2bf(a.x); r.u[1] = f2bf(a.y); r.u[2] = f2bf(a.z); r.u[3] = f2bf(a.w);
        r.u[4] = f2bf(b.x); r.u[5] = f2bf(b.y); r.u[6] = f2bf(b.z); r.u[7] = f2bf(b.w);
        reinterpret_cast<uvec4*>(tab)[i] = r.v;
    }
}

// ============ Kernel 2: bf16 main — quarter-wave per entry, 8-deep MLP ==
// lane = 16*qtr + pos ; pos covers dims [8*pos .. 8*pos+7] (16B of bf16)
// 32 entries per wave-iteration -> 8 independent 16B gathers in flight/lane.
__global__ __launch_bounds__(256) void seg_embed_bf16(
    const int2* __restrict__ pack,
    const int*  __restrict__ ptr,
    const unsigned short* __restrict__ tab,
    float* __restrict__ out, int nnz)
{
    const int lane = threadIdx.x & 63;
    const int wave = threadIdx.x >> 6;
    const int row  = blockIdx.x * 4 + wave;
    const int qtr  = lane >> 4;
    const int pos  = lane & 15;

    const int start = __builtin_amdgcn_readfirstlane(ptr[row]);
    const int end   = __builtin_amdgcn_readfirstlane(ptr[row + 1]);

    float acc[8] = {0.f,0.f,0.f,0.f,0.f,0.f,0.f,0.f};

    for (int j = start; j < end; j += 32) {
        int   c[8];
        float v[8];
        uint4 e[8];
#pragma unroll
        for (int u = 0; u < 8; ++u) {
            const int  idx = j + 4 * u + qtr;
            const int  il  = idx < nnz ? idx : nnz - 1;
            const int2 p   = pack[il];
            const bool ok  = idx < end;
            c[u] = ok ? p.x : 0;
            v[u] = ok ? __int_as_float(p.y) : 0.0f;
        }
#pragma unroll
        for (int u = 0; u < 8; ++u) {
            e[u] = *reinterpret_cast<const uint4*>(
                       tab + (size_t)c[u] * EMBED_DIM + 8 * pos);
        }
        __builtin_amdgcn_sched_barrier(0);   // all 8 gathers issued before FMAs
#pragma unroll
        for (int u = 0; u < 8; ++u) {
#pragma unroll
            for (int k = 0; k < 4; ++k) {
                const unsigned w  = ((const unsigned*)&e[u])[k];
                const float lo = __uint_as_float(w << 16);
                const float hi = __uint_as_float(w & 0xffff0000u);
                acc[2*k]   = fmaf(v[u], lo, acc[2*k]);
                acc[2*k+1] = fmaf(v[u], hi, acc[2*k+1]);
            }
        }
    }

#pragma unroll
    for (int k = 0; k < 8; ++k) {
        acc[k] += __shfl_xor(acc[k], 16, 64);
        acc[k] += __shfl_xor(acc[k], 32, 64);
    }
    if (qtr == 0) {
        float* o = out + (size_t)row * EMBED_DIM + 8 * pos;
        *reinterpret_cast<float4*>(o)     = make_float4(acc[0], acc[1], acc[2], acc[3]);
        *reinterpret_cast<float4*>(o + 4) = make_float4(acc[4], acc[5], acc[6], acc[7]);
    }
}

// ============ Fallback (ws too small for bf16 table): f32 path ==========
__global__ __launch_bounds__(256) void seg_embed_f32(
    const int2* __restrict__ pack,
    const int*  __restrict__ ptr,
    const float* __restrict__ emb,
    float* __restrict__ out, int nnz)
{
    const int lane = threadIdx.x & 63;
    const int wave = threadIdx.x >> 6;
    const int row  = blockIdx.x * 4 + wave;
    const int half = lane >> 5;
    const int q    = lane & 31;

    const int start = __builtin_amdgcn_readfirstlane(ptr[row]);
    const int end   = __builtin_amdgcn_readfirstlane(ptr[row + 1]);

    float4 acc = make_float4(0.f, 0.f, 0.f, 0.f);

    for (int j = start; j < end; j += 8) {
        int    c[4];
        float  v[4];
        float4 e[4];
#pragma unroll
        for (int u = 0; u < 4; ++u) {
            const int  idx = j + 2 * u + half;
            const int  il  = idx < nnz ? idx : nnz - 1;
            const int2 p   = pack[il];
            const bool ok  = idx < end;
            c[u] = ok ? p.x : 0;
            v[u] = ok ? __int_as_float(p.y) : 0.0f;
        }
#pragma unroll
        for (int u = 0; u < 4; ++u) {
            e[u] = *reinterpret_cast<const float4*>(
                       emb + (size_t)c[u] * EMBED_DIM + 4 * q);
        }
        __builtin_amdgcn_sched_barrier(0);
#pragma unroll
        for (int u = 0; u < 4; ++u) {
            acc.x = fmaf(v[u], e[u].x, acc.x);
            acc.y = fmaf(v[u], e[u].y, acc.y);
            acc.z = fmaf(v[u], e[u].z, acc.z);
            acc.w = fmaf(v[u], e[u].w, acc.w);
        }
    }

    acc.x += __shfl_xor(acc.x, 32, 64);
    acc.y += __shfl_xor(acc.y, 32, 64);
    acc.z += __shfl_xor(acc.z, 32, 64);
    acc.w += __shfl_xor(acc.w, 32, 64);
    if (half == 0) {
        *reinterpret_cast<float4*>(out + (size_t)row * EMBED_DIM + 4 * q) = acc;
    }
}

extern "C" void kernel_launch(void* const* d_in, const int* in_sizes, int n_in,
                              void* d_out, int out_size, void* d_ws, size_t ws_size,
                              hipStream_t stream) {
    const int*   row_idx = (const int*)  d_in[0];
    const int*   col_idx = (const int*)  d_in[1];
    const float* data    = (const float*)d_in[2];
    const float* emb     = (const float*)d_in[3];
    const int*   keep    = (const int*)  d_in[4];
    float*       out     = (float*)d_out;
    const int    nnz     = in_sizes[0];
    const int    nitems  = in_sizes[3] / EMBED_DIM;

    const size_t ptr_bytes  = (size_t)(NUM_IDS + 1) * sizeof(int);
    const size_t pack_off   = (ptr_bytes + 255) & ~(size_t)255;
    const size_t pack_bytes = (size_t)nnz * sizeof(int2);
    const size_t tab_off    = (pack_off + pack_bytes + 255) & ~(size_t)255;
    const size_t tab_bytes  = (size_t)nitems * EMBED_DIM * sizeof(unsigned short);

    const int grid    = NUM_IDS / 4;
    const int nb_meta = (nnz + 255) / 256;

    if (ws_size >= tab_off + tab_bytes) {
        int*            ptr  = (int*)d_ws;
        int2*           pack = (int2*)((char*)d_ws + pack_off);
        unsigned short* tab  = (unsigned short*)((char*)d_ws + tab_off);
        const int n8      = nitems * EMBED_DIM / 8;
        const int nb_conv = (n8 + 255) / 256;
        prep_fused<<<nb_meta + nb_conv, 256, 0, stream>>>(
            row_idx, col_idx, data, keep, nnz, ptr, pack, emb, tab, n8, nb_meta);
        seg_embed_bf16<<<grid, 256, 0, stream>>>(pack, ptr, tab, out, nnz);
    } else if (ws_size >= pack_off + pack_bytes) {
        int*  ptr  = (int*)d_ws;
        int2* pack = (int2*)((char*)d_ws + pack_off);
        prep_fused<<<nb_meta, 256, 0, stream>>>(
            row_idx, col_idx, data, keep, nnz, ptr, pack,
            emb, (unsigned short*)nullptr, 0, nb_meta);
        seg_embed_f32<<<grid, 256, 0, stream>>>(pack, ptr, emb, out, nnz);
    }
}